// Round 3
// baseline (17.916 us; speedup 1.0000x reference)
//
#include <hip/hip_runtime.h>

typedef float v2f __attribute__((ext_vector_type(2)));

#define IN_F 4096
#define OUT_F 11008
#define GROUPSIZE 128
#define NGROUPS 32        // IN_F / GROUPSIZE
#define QROWS 512         // IN_F / 8
#define ZCOLS 1376        // OUT_F / 8
#define WS_NEW_BYTES ((size_t)NGROUPS * 4 * OUT_F * sizeof(float))
#define WS_OLD_BYTES ((size_t)8 * 4 * OUT_F * sizeof(float))

// ============ Stage 1 (new): grid (OUT_F/256, NGROUPS), block 256 ============
// Block = 4 waves; wave kq handles k-quarter (4 packed rows) of group g.
// Lane owns 4 consecutive columns -> int4 qweight loads, float2 packed math.
__global__ __launch_bounds__(256) void gptq_s1(
    const float* __restrict__ x,       // [4, IN_F]
    const float* __restrict__ scales,  // [NGROUPS, OUT_F]
    const int*   __restrict__ qweight, // [QROWS, OUT_F]
    const int*   __restrict__ qzeros,  // [NGROUPS, ZCOLS]
    float*       __restrict__ ws)      // [NGROUPS, 4, OUT_F]
{
    __shared__ float part[4][4][256];  // [kq][m][col] = 16 KB

    const int tid  = threadIdx.x;
    const int lane = tid & 63;
    const int kq   = __builtin_amdgcn_readfirstlane(tid >> 6);  // 0..3 uniform
    const int c0   = blockIdx.x * 256 + lane * 4;
    const int g    = blockIdx.y;

    // zeros for the 4 columns (single dword covers them: c0 % 4 == 0)
    const unsigned qz  = (unsigned)qzeros[g * ZCOLS + (c0 >> 3)];
    const unsigned zsh = 4u * (unsigned)(c0 & 7);
    v2f zz[4];
    #pragma unroll
    for (int c = 0; c < 4; ++c) {
        const float zf = (float)(((qz >> (zsh + 4u * c)) & 0xFu) + 1u);
        zz[c].x = zf; zz[c].y = zf;
    }

    const float4 sc4 = *(const float4*)(scales + g * OUT_F + c0);

    const int row0 = g * 16 + kq * 4;  // 4 packed rows per wave
    v2f acc[4][4] = {};                // [m][c], pairs over k

    #pragma unroll
    for (int t = 0; t < 4; ++t) {
        const int row = row0 + t;
        const int4 w4 = *(const int4*)(qweight + row * OUT_F + c0);
        const int k0  = row * 8;       // wave-uniform

        // x pairs, wave-uniform addresses -> scalar loads
        v2f xp[4][4];
        #pragma unroll
        for (int m = 0; m < 4; ++m)
            #pragma unroll
            for (int jj = 0; jj < 4; ++jj)
                xp[m][jj] = *(const v2f*)(x + m * IN_F + k0 + 2 * jj);

        const unsigned wv[4] = {(unsigned)w4.x, (unsigned)w4.y,
                                (unsigned)w4.z, (unsigned)w4.w};
        #pragma unroll
        for (int c = 0; c < 4; ++c) {
            const unsigned w  = wv[c];
            const unsigned lo = w & 0x0F0F0F0Fu;         // nibbles 0,2,4,6
            const unsigned hi = (w >> 4) & 0x0F0F0F0Fu;  // nibbles 1,3,5,7
            v2f d[4];
            d[0].x = (float)(lo & 0xFFu);         d[0].y = (float)(hi & 0xFFu);
            d[1].x = (float)((lo >> 8) & 0xFFu);  d[1].y = (float)((hi >> 8) & 0xFFu);
            d[2].x = (float)((lo >> 16) & 0xFFu); d[2].y = (float)((hi >> 16) & 0xFFu);
            d[3].x = (float)(lo >> 24);           d[3].y = (float)(hi >> 24);
            #pragma unroll
            for (int jj = 0; jj < 4; ++jj) d[jj] = d[jj] - zz[c];
            #pragma unroll
            for (int m = 0; m < 4; ++m) {
                acc[m][c] += xp[m][0] * d[0];
                acc[m][c] += xp[m][1] * d[1];
                acc[m][c] += xp[m][2] * d[2];
                acc[m][c] += xp[m][3] * d[3];
            }
        }
    }

    #pragma unroll
    for (int m = 0; m < 4; ++m) {
        float4 r;
        r.x = (acc[m][0].x + acc[m][0].y) * sc4.x;
        r.y = (acc[m][1].x + acc[m][1].y) * sc4.y;
        r.z = (acc[m][2].x + acc[m][2].y) * sc4.z;
        r.w = (acc[m][3].x + acc[m][3].y) * sc4.w;
        *(float4*)&part[kq][m][lane * 4] = r;
    }
    __syncthreads();

    // Reduce 4 k-quarters: thread -> (m = tid>>6, 4 cols)
    const int m  = tid >> 6;
    const int cc = (tid & 63) * 4;
    float4 a = *(const float4*)&part[0][m][cc];
    const float4 b = *(const float4*)&part[1][m][cc];
    const float4 c2 = *(const float4*)&part[2][m][cc];
    const float4 d2 = *(const float4*)&part[3][m][cc];
    a.x += b.x + c2.x + d2.x;
    a.y += b.y + c2.y + d2.y;
    a.z += b.z + c2.z + d2.z;
    a.w += b.w + c2.w + d2.w;
    *(float4*)(ws + (g * 4 + m) * OUT_F + blockIdx.x * 256 + cc) = a;
}

// ============ Stage 2 (new): reduce NGROUPS partials + bias ============
__global__ __launch_bounds__(256) void gptq_s2(
    const float* __restrict__ ws,      // [NGROUPS, 4, OUT_F]
    const float* __restrict__ bias,
    float*       __restrict__ out)     // [4, OUT_F]
{
    const int n = blockIdx.x * 256 + threadIdx.x;
    const int m = blockIdx.y;
    float s0 = bias[n], s1 = 0.f, s2 = 0.f, s3 = 0.f;
    #pragma unroll
    for (int g = 0; g < NGROUPS; g += 4) {
        s0 += ws[((g + 0) * 4 + m) * OUT_F + n];
        s1 += ws[((g + 1) * 4 + m) * OUT_F + n];
        s2 += ws[((g + 2) * 4 + m) * OUT_F + n];
        s3 += ws[((g + 3) * 4 + m) * OUT_F + n];
    }
    out[m * OUT_F + n] = (s0 + s1) + (s2 + s3);
}

// ============ Fallback A: round-2 two-stage (ws >= 1.41 MB) ============
__global__ __launch_bounds__(256) void gptq_partial_kernel(
    const float* __restrict__ x, const float* __restrict__ scales,
    const int* __restrict__ qweight, const int* __restrict__ qzeros,
    float* __restrict__ ws)
{
    __shared__ float part[4][4][64];
    const int tid = threadIdx.x;
    const int col = tid & 63;
    const int kp  = tid >> 6;
    const int n   = blockIdx.x * 64 + col;
    const int g   = blockIdx.y * 4 + kp;
    const int gu  = __builtin_amdgcn_readfirstlane(g);
    const unsigned qz = (unsigned)qzeros[g * ZCOLS + (n >> 3)];
    const float zf = (float)(((qz >> (4u * (unsigned)(n & 7))) & 0xFu) + 1u);
    const float sc = scales[g * OUT_F + n];
    float ga[4] = {0.f, 0.f, 0.f, 0.f};
    const int kkbase = gu * (GROUPSIZE / 8);
    #pragma unroll
    for (int t = 0; t < GROUPSIZE / 8; ++t) {
        const int kk = kkbase + t;
        const unsigned w = (unsigned)qweight[kk * OUT_F + n];
        const unsigned lo = w & 0x0F0F0F0Fu;
        const unsigned hi = (w >> 4) & 0x0F0F0F0Fu;
        float q[8];
        q[0] = (float)(lo & 0xFFu);         q[1] = (float)(hi & 0xFFu);
        q[2] = (float)((lo >> 8) & 0xFFu);  q[3] = (float)((hi >> 8) & 0xFFu);
        q[4] = (float)((lo >> 16) & 0xFFu); q[5] = (float)((hi >> 16) & 0xFFu);
        q[6] = (float)(lo >> 24);           q[7] = (float)(hi >> 24);
        const int k0 = kk * 8;
        #pragma unroll
        for (int j = 0; j < 8; ++j) {
            const float d = q[j] - zf;
            #pragma unroll
            for (int m = 0; m < 4; ++m) ga[m] += x[m * IN_F + k0 + j] * d;
        }
    }
    #pragma unroll
    for (int m = 0; m < 4; ++m) part[kp][m][col] = sc * ga[m];
    __syncthreads();
    const int m = tid >> 6;
    const int c = tid & 63;
    const int nn = blockIdx.x * 64 + c;
    const float s = part[0][m][c] + part[1][m][c] + part[2][m][c] + part[3][m][c];
    ws[(blockIdx.y * 4 + m) * OUT_F + nn] = s;
}

__global__ __launch_bounds__(256) void gptq_reduce_kernel(
    const float* __restrict__ ws, const float* __restrict__ bias,
    float* __restrict__ out)
{
    const int n = blockIdx.x * 256 + threadIdx.x;
    const int m = blockIdx.y;
    float s = bias[n];
    #pragma unroll
    for (int ks = 0; ks < 8; ++ks) s += ws[(ks * 4 + m) * OUT_F + n];
    out[m * OUT_F + n] = s;
}

// ============ Fallback B: fused single kernel (no ws) ============
__global__ __launch_bounds__(256) void gptq_gemv_fused(
    const float* __restrict__ x, const float* __restrict__ scales,
    const float* __restrict__ bias, const int* __restrict__ qweight,
    const int* __restrict__ qzeros, float* __restrict__ out)
{
    __shared__ float part[4][4][64];
    const int tid = threadIdx.x;
    const int col = tid & 63;
    const int kp  = tid >> 6;
    const int n   = blockIdx.x * 64 + col;
    const unsigned zshift = 4u * (unsigned)(n & 7);
    const int zcol = n >> 3;
    float acc[4] = {0.f, 0.f, 0.f, 0.f};
    for (int g = kp * 8; g < kp * 8 + 8; ++g) {
        const unsigned qz = (unsigned)qzeros[g * ZCOLS + zcol];
        const float zf = (float)(((qz >> zshift) & 0xFu) + 1u);
        const float sc = scales[g * OUT_F + n];
        float ga[4] = {0.f, 0.f, 0.f, 0.f};
        #pragma unroll 4
        for (int t = 0; t < 16; ++t) {
            const int kk = g * 16 + t;
            const unsigned w = (unsigned)qweight[kk * OUT_F + n];
            const unsigned lo = w & 0x0F0F0F0Fu;
            const unsigned hi = (w >> 4) & 0x0F0F0F0Fu;
            float q[8];
            q[0] = (float)(lo & 0xFFu);         q[1] = (float)(hi & 0xFFu);
            q[2] = (float)((lo >> 8) & 0xFFu);  q[3] = (float)((hi >> 8) & 0xFFu);
            q[4] = (float)((lo >> 16) & 0xFFu); q[5] = (float)((hi >> 16) & 0xFFu);
            q[6] = (float)(lo >> 24);           q[7] = (float)(hi >> 24);
            const int k0 = kk * 8;
            #pragma unroll
            for (int j = 0; j < 8; ++j) {
                const float d = q[j] - zf;
                #pragma unroll
                for (int m = 0; m < 4; ++m) ga[m] += x[m * IN_F + k0 + j] * d;
            }
        }
        #pragma unroll
        for (int m = 0; m < 4; ++m) acc[m] += sc * ga[m];
    }
    #pragma unroll
    for (int m = 0; m < 4; ++m) part[kp][m][col] = acc[m];
    __syncthreads();
    const int m = tid >> 6;
    const int c = tid & 63;
    const int nn = blockIdx.x * 64 + c;
    const float s = part[0][m][c] + part[1][m][c] + part[2][m][c] + part[3][m][c];
    out[m * OUT_F + nn] = s + bias[nn];
}

extern "C" void kernel_launch(void* const* d_in, const int* in_sizes, int n_in,
                              void* d_out, int out_size, void* d_ws, size_t ws_size,
                              hipStream_t stream) {
    const float* x       = (const float*)d_in[0];
    const float* scales  = (const float*)d_in[1];
    const float* bias    = (const float*)d_in[2];
    const int*   qweight = (const int*)d_in[3];
    const int*   qzeros  = (const int*)d_in[4];
    float*       out     = (float*)d_out;

    if (ws_size >= WS_NEW_BYTES) {
        float* ws = (float*)d_ws;
        dim3 g1(OUT_F / 256, NGROUPS);   // (43, 32) = 1376 blocks
        gptq_s1<<<g1, 256, 0, stream>>>(x, scales, qweight, qzeros, ws);
        dim3 g2(OUT_F / 256, 4);         // (43, 4)
        gptq_s2<<<g2, 256, 0, stream>>>(ws, bias, out);
    } else if (ws_size >= WS_OLD_BYTES) {
        float* ws = (float*)d_ws;
        dim3 g1(OUT_F / 64, 8);
        gptq_partial_kernel<<<g1, 256, 0, stream>>>(x, scales, qweight, qzeros, ws);
        dim3 g2(OUT_F / 256, 4);
        gptq_reduce_kernel<<<g2, 256, 0, stream>>>(ws, bias, out);
    } else {
        dim3 grid(OUT_F / 64);
        gptq_gemv_fused<<<grid, 256, 0, stream>>>(x, scales, bias, qweight, qzeros, out);
    }
}